// Round 1
// baseline (241.097 us; speedup 1.0000x reference)
//
#include <hip/hip_runtime.h>
#include <hip/hip_bf16.h>
#include <math.h>

#define B_ 4
#define T_ 2048
#define C_ 1024
#define H_ 16
#define D_ 64
#define BT (B_*T_)
#define BH (B_*H_)

typedef __bf16 bf16x8 __attribute__((ext_vector_type(8)));
typedef __bf16 bf16x4 __attribute__((ext_vector_type(4)));
typedef float f32x4 __attribute__((ext_vector_type(4)));
typedef unsigned short u16;
typedef u16 u16x8 __attribute__((ext_vector_type(8)));

// async global->LDS, 16B/lane; LDS dest = wave-uniform base + lane*16
#define GLL(g, l) __builtin_amdgcn_global_load_lds( \
    (const __attribute__((address_space(1))) unsigned int*)(g), \
    (__attribute__((address_space(3))) unsigned int*)(l), 16, 0, 0)

#define SCALE2 0.04508422f  // C^-0.5 * log2(e), folded into Wq

#define SBAR()   do { asm volatile("" ::: "memory"); __builtin_amdgcn_s_barrier(); asm volatile("" ::: "memory"); } while (0)
#define WAITV(n) asm volatile("s_waitcnt vmcnt(" #n ")" ::: "memory")
#define LGKM0()  asm volatile("s_waitcnt lgkmcnt(0)" ::: "memory")

__device__ __forceinline__ u16 f2b(float f) {
    union { float f; unsigned u; } v; v.f = f;
    unsigned r = v.u + 0x7fffu + ((v.u >> 16) & 1u);
    return (u16)(r >> 16);
}

// ---- fused preprocessing: cast x, cast Wo, transpose+scale Wq/Wk/Wv ------
// blocks [0,8192): x fp32->bf16 ; [8192,9216): Wo ; [9216,9984): transpose_w
__global__ __launch_bounds__(256) void prep(const float* __restrict__ x,
                                            const float* __restrict__ Wo,
                                            const float* __restrict__ Wq,
                                            const float* __restrict__ Wk,
                                            const float* __restrict__ Wv,
                                            u16* __restrict__ xbf,
                                            u16* __restrict__ wobf,
                                            u16* __restrict__ wt) {
    __shared__ u16 lds[64][72];
    int bid = blockIdx.x, tid = threadIdx.x;
    if (bid < 8192) {
        int g = bid * 256 + tid;
        float4 v = ((const float4*)x)[g];
        ushort4 o;
        o.x = f2b(v.x); o.y = f2b(v.y); o.z = f2b(v.z); o.w = f2b(v.w);
        ((ushort4*)xbf)[g] = o;
        return;
    }
    if (bid < 9216) {
        int g = (bid - 8192) * 256 + tid;
        float4 v = ((const float4*)Wo)[g];
        ushort4 o;
        o.x = f2b(v.x); o.y = f2b(v.y); o.z = f2b(v.z); o.w = f2b(v.w);
        ((ushort4*)wobf)[g] = o;
        return;
    }
    int id = bid - 9216;              // 0..767
    int cb = id & 15, h = (id >> 4) & 15, w = id >> 8;
    const float* W = (w == 0) ? Wq : (w == 1) ? Wk : Wv;
    float sc = (w == 0) ? SCALE2 : 1.0f;
    int c0 = cb * 64;
    {
        int col = (tid & 15) * 4;
        for (int cc = 0; cc < 4; ++cc) {
            int r = (tid >> 4) + cc * 16;
            float4 v = *(const float4*)&W[(size_t)(h * C_ + c0 + r) * D_ + col];
            lds[r][col + 0] = f2b(v.x * sc); lds[r][col + 1] = f2b(v.y * sc);
            lds[r][col + 2] = f2b(v.z * sc); lds[r][col + 3] = f2b(v.w * sc);
        }
    }
    __syncthreads();
    {
        int tcol = (tid & 7) * 8;
        for (int cc = 0; cc < 2; ++cc) {
            int d = (tid >> 3) + cc * 32;
            u16x8 t;
            for (int j = 0; j < 8; ++j) t[j] = lds[tcol + j][d];
            *(u16x8*)&wt[(((size_t)(w * H_ + h) * D_ + d) * C_) + c0 + tcol] = t;
        }
    }
}

// ------- fused QKV GEMM, 8-phase counted-vmcnt schedule -------------------
// x[8192,1024] x wt[3072,1024]^T -> q,k [BH,T,D]; V transposed to vt [BH,D,T].
// BM=256 BN=192 BK=64, 512 thr = 8 waves (2M x 4N), grid 32x16 = 512 blocks
// = exactly 2 full rounds on 256 CUs (no tail). LDS 112 KiB double-buffered.
// Per K-tile, 4 phases; B-frags ds_read only in p0 (held in regs p1-p3), so
// cur-buffer B region is dead after p0:
//   p0: read B(all)+A(r0,1); stage A(t+1)u0,u1 -> nxt    | 12 MFMA (rows 0,1)
//   p1: read A(r2,3);        stage A(t+1)u2,u3 -> nxt    | 12 MFMA
//   p2: read A(r4,5);        stage B(t+2)u0,u1 -> cur.B  | 12 MFMA
//   p3: read A(r6,7);        stage B(t+2)u2    -> cur.B  | 12 MFMA, vmcnt(3)
// vmcnt(3) allows B(t+2)'s 3 GLL to stay in flight across the tile boundary
// (never drains to 0 in the main loop); guarantees A(t+1)+B(t+1) landed.
#define NT_ 16
__global__ __launch_bounds__(512, 2) void qkv_gemm(const u16* __restrict__ xbf,
                                                   const u16* __restrict__ wt,
                                                   u16* __restrict__ q, u16* __restrict__ k,
                                                   u16* __restrict__ vt) {
    __shared__ u16 Al[2][256][64];   // 64 KiB
    __shared__ u16 Bl[2][192][64];   // 48 KiB
    int orig = blockIdx.x;
    int wg = (orig & 7) * 64 + (orig >> 3);   // XCD swizzle, bijective (512%8==0)
    int mb = wg & 31, nb = wg >> 5;           // 32 M-tiles x 16 N-tiles
    int tid = threadIdx.x, wid = tid >> 6, lane = tid & 63;
    int l15 = lane & 15, quad = lane >> 4;
    int wm = wid >> 2, wn = wid & 3;          // wave tile: 128 x 48
    int srow8 = wid * 8 + (lane >> 3);        // 0..63: block-cooperative 64-row unit
    int scol8 = ((lane & 7) ^ (lane >> 3)) * 8;  // pre-swizzled source column
    const u16* Ag = xbf + (size_t)(mb * 256 + srow8) * C_ + scol8;
    const u16* Bg = wt  + (size_t)(nb * 192 + srow8) * C_ + scol8;
    int rsw = l15 & 7;
    f32x4 acc[8][3];
    #pragma unroll
    for (int i = 0; i < 8; ++i)
        #pragma unroll
        for (int j = 0; j < 3; ++j) acc[i][j] = (f32x4){0.f, 0.f, 0.f, 0.f};

#define STAGE_A(buf, u, kt) GLL(Ag + (size_t)((u) * 64) * C_ + (kt) * 64, &Al[buf][(u) * 64 + wid * 8][0])
#define STAGE_B(buf, u, kt) GLL(Bg + (size_t)((u) * 64) * C_ + (kt) * 64, &Bl[buf][(u) * 64 + wid * 8][0])
#define LOAD_A(R0) do { \
    _Pragma("unroll") for (int r = 0; r < 2; ++r) \
    _Pragma("unroll") for (int ks = 0; ks < 2; ++ks) \
        a[r][ks] = *(const bf16x8*)&Ac[wm * 128 + ((R0) + r) * 16 + l15][(((ks << 2) | quad) ^ rsw) * 8]; \
} while (0)
#define MFMA_PH(R0) do { \
    __builtin_amdgcn_s_setprio(1); \
    _Pragma("unroll") for (int ks = 0; ks < 2; ++ks) \
    _Pragma("unroll") for (int fc = 0; fc < 3; ++fc) \
    _Pragma("unroll") for (int r = 0; r < 2; ++r) \
        acc[(R0) + r][fc] = __builtin_amdgcn_mfma_f32_16x16x32_bf16(a[r][ks], b[fc][ks], acc[(R0) + r][fc], 0, 0, 0); \
    __builtin_amdgcn_s_setprio(0); \
} while (0)

    // prologue: A(t0) u0-3, B(t0) u0-2, B(t1) u0-2 = 10 GLL; first 7 must land
    STAGE_A(0, 0, 0); STAGE_A(0, 1, 0); STAGE_A(0, 2, 0); STAGE_A(0, 3, 0);
    STAGE_B(0, 0, 0); STAGE_B(0, 1, 0); STAGE_B(0, 2, 0);
    STAGE_B(1, 0, 1); STAGE_B(1, 1, 1); STAGE_B(1, 2, 1);
    WAITV(3);
    SBAR();

    for (int t = 0; t < NT_; ++t) {
        int cur = t & 1, nxt = cur ^ 1;
        const u16 (*Ac)[64] = Al[cur];
        const u16 (*Bc)[64] = Bl[cur];
        bf16x8 b[3][2], a[2][2];
        // ---- phase 0: all B frags + A rows 0,1 -------------------------
        #pragma unroll
        for (int fc = 0; fc < 3; ++fc)
            #pragma unroll
            for (int ks = 0; ks < 2; ++ks)
                b[fc][ks] = *(const bf16x8*)&Bc[wn * 48 + fc * 16 + l15][(((ks << 2) | quad) ^ rsw) * 8];
        LOAD_A(0);
        if (t + 1 < NT_) { STAGE_A(nxt, 0, t + 1); STAGE_A(nxt, 1, t + 1); }
        SBAR(); LGKM0();
        MFMA_PH(0);
        SBAR();
        // ---- phase 1: A rows 2,3 ---------------------------------------
        LOAD_A(2);
        if (t + 1 < NT_) { STAGE_A(nxt, 2, t + 1); STAGE_A(nxt, 3, t + 1); }
        SBAR(); LGKM0();
        MFMA_PH(2);
        SBAR();
        // ---- phase 2: A rows 4,5; cur.B is dead after p0 ---------------
        LOAD_A(4);
        if (t + 2 < NT_) { STAGE_B(cur, 0, t + 2); STAGE_B(cur, 1, t + 2); }
        SBAR(); LGKM0();
        MFMA_PH(4);
        SBAR();
        // ---- phase 3: A rows 6,7; counted vmcnt at tile boundary -------
        LOAD_A(6);
        if (t + 2 < NT_) STAGE_B(cur, 2, t + 2);
        SBAR(); LGKM0();
        MFMA_PH(6);
        if (t + 2 < NT_)      WAITV(3);
        else if (t + 1 < NT_) WAITV(0);
        SBAR();
    }
#undef STAGE_A
#undef STAGE_B
#undef LOAD_A
#undef MFMA_PH

    // epilogue: n = nb*192 + wn*48 + fc*16 + l15 decodes to {q|k|v, head, d}
    int bb = mb >> 3;                       // 256-row block within one batch
    int mbase0 = mb * 256 + wm * 128;
    #pragma unroll
    for (int fc = 0; fc < 3; ++fc) {
        int n0 = nb * 192 + wn * 48 + fc * 16;
        int wsel = n0 >> 10, hh = (n0 >> 6) & 15, d0 = n0 & 63;
        if (wsel == 2) {
            // V: store transposed to vt[bh][d][t], 4 consecutive t per pack
            u16* vrow = vt + ((size_t)((bb * H_ + hh) * D_) + d0 + l15) * T_;
            #pragma unroll
            for (int fr = 0; fr < 8; ++fr) {
                int tbase = ((mbase0 + fr * 16) & (T_ - 1)) + quad * 4;
                bf16x4 w;
                #pragma unroll
                for (int r = 0; r < 4; ++r) w[r] = (__bf16)acc[fr][fc][r];
                *(bf16x4*)&vrow[tbase] = w;
            }
        } else {
            u16* op = wsel ? k : q;
            #pragma unroll
            for (int fr = 0; fr < 8; ++fr)
                #pragma unroll
                for (int r = 0; r < 4; ++r) {
                    int m = mbase0 + fr * 16 + quad * 4 + r;
                    int tt = m & (T_ - 1);
                    op[((size_t)(bb * H_ + hh) * T_ + tt) * D_ + d0 + l15] = f2b(acc[fr][fc][r]);
                }
        }
    }
}

// -------- flash attention v5: fixed-base softmax (no online max) ----------
// P = exp2(s) directly: scores pre-scaled into exp2 domain; |s| << 128 for
// N(0,1)-class inputs so no overflow; max-subtraction cancels in P/l.
// Block-cooperative GLL K/V staging, double-buffered, one barrier/tile,
// XCD-affine grid (BH,16).
__global__ __launch_bounds__(256, 2) void attn(const u16* __restrict__ q, const u16* __restrict__ kk,
                                               const u16* __restrict__ vt, u16* __restrict__ att) {
    __shared__ u16 Kl[2][64][64];
    __shared__ u16 Vl[2][64][64];
    __shared__ u16 Pl[4][32][72];
    int bh = blockIdx.x, c = 15 - blockIdx.y;
    int b = bh >> 4, h = bh & 15;
    int tid = threadIdx.x, wid = tid >> 6, lane = tid & 63, l15 = lane & 15, quad = lane >> 4;
    const u16* qbase = q + (size_t)bh * T_ * D_;
    const u16* kbase = kk + (size_t)bh * T_ * D_;
    const u16* vbase = vt + (size_t)bh * D_ * T_;
    u16* pw = &Pl[wid][0][0];
    bf16x8 ones;
    #pragma unroll
    for (int j = 0; j < 8; ++j) ones[j] = (__bf16)1.0f;
    int r8 = lane >> 3, cbl_st = lane & 7;
    int csrc = ((cbl_st ^ r8)) * 8;
    int strow = wid * 16 + r8;
    int rsw = l15 & 7;

    int R0q = c * 128 + wid * 32;
    int ktb = 2 * c + 1;
    int kmax_w = R0q >> 6;
    bf16x8 bq[2][2];
    #pragma unroll
    for (int qt = 0; qt < 2; ++qt)
        #pragma unroll
        for (int kd = 0; kd < 2; ++kd)
            bq[qt][kd] = *(const bf16x8*)&qbase[(size_t)(R0q + qt * 16 + l15) * D_ + kd * 32 + quad * 8];
    f32x4 o[4][2];
    f32x4 lacc[2];
    #pragma unroll
    for (int dt = 0; dt < 4; ++dt)
        #pragma unroll
        for (int qt = 0; qt < 2; ++qt) o[dt][qt] = (f32x4){0.f, 0.f, 0.f, 0.f};
    lacc[0] = (f32x4){0.f, 0.f, 0.f, 0.f};
    lacc[1] = (f32x4){0.f, 0.f, 0.f, 0.f};
    #pragma unroll
    for (int j = 0; j < 2; ++j) {
        GLL(kbase + (size_t)(strow + j * 8) * D_ + csrc, &Kl[0][wid * 16 + j * 8][0]);
        GLL(vbase + (size_t)(strow + j * 8) * T_ + csrc, &Vl[0][wid * 16 + j * 8][0]);
    }
    __syncthreads();
    for (int kt = 0; kt <= ktb; ++kt) {
        int cur = kt & 1;
        if (kt < ktb) {
            int kn = (kt + 1) * 64;
            #pragma unroll
            for (int j = 0; j < 2; ++j) {
                GLL(kbase + (size_t)(kn + strow + j * 8) * D_ + csrc, &Kl[cur ^ 1][wid * 16 + j * 8][0]);
                GLL(vbase + (size_t)(strow + j * 8) * T_ + kn + csrc, &Vl[cur ^ 1][wid * 16 + j * 8][0]);
            }
        }
        if (kt <= kmax_w) {
            int k0 = kt * 64;
            f32x4 sS[4][2];
            #pragma unroll
            for (int kvt = 0; kvt < 4; ++kvt)
                #pragma unroll
                for (int qt = 0; qt < 2; ++qt) sS[kvt][qt] = (f32x4){0.f, 0.f, 0.f, 0.f};
            #pragma unroll
            for (int kd = 0; kd < 2; ++kd) {
                int cblk = (((kd << 2) | quad) ^ rsw) * 8;
                bf16x8 akf[4];
                #pragma unroll
                for (int kvt = 0; kvt < 4; ++kvt)
                    akf[kvt] = *(const bf16x8*)&Kl[cur][kvt * 16 + l15][cblk];
                #pragma unroll
                for (int kvt = 0; kvt < 4; ++kvt)
                    #pragma unroll
                    for (int qt = 0; qt < 2; ++qt)
                        sS[kvt][qt] = __builtin_amdgcn_mfma_f32_16x16x32_bf16(akf[kvt], bq[qt][kd], sS[kvt][qt], 0, 0, 0);
            }
            if (kt == kmax_w) {  // causal mask, diagonal tile only
                #pragma unroll
                for (int qt = 0; qt < 2; ++qt) {
                    int qabs = R0q + qt * 16 + l15;
                    #pragma unroll
                    for (int kvt = 0; kvt < 4; ++kvt) {
                        int kvb = k0 + kvt * 16 + quad * 4;
                        #pragma unroll
                        for (int r = 0; r < 4; ++r)
                            if (kvb + r > qabs) sS[kvt][qt][r] = -INFINITY;
                    }
                }
            }
            // fixed-base softmax: P = exp2(s); exp2(-inf) = 0 handles the mask
            #pragma unroll
            for (int kvt = 0; kvt < 4; ++kvt)
                #pragma unroll
                for (int qt = 0; qt < 2; ++qt)
                    #pragma unroll
                    for (int r = 0; r < 4; ++r)
                        sS[kvt][qt][r] = __builtin_amdgcn_exp2f(sS[kvt][qt][r]);
            // P -> wave-private LDS: P[qrow][kv] (bf16)
            #pragma unroll
            for (int qt = 0; qt < 2; ++qt)
                #pragma unroll
                for (int kvt = 0; kvt < 4; ++kvt) {
                    bf16x4 w;
                    #pragma unroll
                    for (int r = 0; r < 4; ++r) w[r] = (__bf16)sS[kvt][qt][r];
                    *(bf16x4*)&pw[(qt * 16 + l15) * 72 + kvt * 16 + quad * 4] = w;
                }
            // O^T += V^T . P^T ; l += ones . P^T
            #pragma unroll
            for (int ks = 0; ks < 2; ++ks) {
                int cblk = (((ks << 2) | quad) ^ rsw) * 8;
                bf16x8 avf[4];
                #pragma unroll
                for (int dt = 0; dt < 4; ++dt)
                    avf[dt] = *(const bf16x8*)&Vl[cur][dt * 16 + l15][cblk];
                #pragma unroll
                for (int qt = 0; qt < 2; ++qt) {
                    bf16x8 bp = *(const bf16x8*)&pw[(qt * 16 + l15) * 72 + ks * 32 + quad * 8];
                    #pragma unroll
                    for (int dt = 0; dt < 4; ++dt)
                        o[dt][qt] = __builtin_amdgcn_mfma_f32_16x16x32_bf16(avf[dt], bp, o[dt][qt], 0, 0, 0);
                    lacc[qt] = __builtin_amdgcn_mfma_f32_16x16x32_bf16(ones, bp, lacc[qt], 0, 0, 0);
                }
            }
        }
        __syncthreads();
    }
    #pragma unroll
    for (int qt = 0; qt < 2; ++qt) {
        float rl = __builtin_amdgcn_rcpf(lacc[qt][0]);
        int qabs = R0q + qt * 16 + l15;
        #pragma unroll
        for (int dt = 0; dt < 4; ++dt) {
            bf16x4 w;
            #pragma unroll
            for (int r = 0; r < 4; ++r) w[r] = (__bf16)(o[dt][qt][r] * rl);
            *(bf16x4*)&att[(size_t)(b * T_ + qabs) * C_ + h * 64 + dt * 16 + quad * 4] = w;
        }
    }
}

// ------ out proj: att[8192,1024] x wo[1024,1024]^T + bo -> fp32 out -------
// Single-buffer GLL staging (R8 config).
__global__ __launch_bounds__(256) void out_gemm(const u16* __restrict__ att,
                                                const u16* __restrict__ wo,
                                                const float* __restrict__ bo,
                                                float* __restrict__ out) {
    __shared__ u16 Al[128][64];
    __shared__ u16 Bl[128][64];
    int mb = blockIdx.x, nb = blockIdx.y;
    int tid = threadIdx.x, wv = tid >> 6, lane = tid & 63, l15 = lane & 15, quad = lane >> 4;
    int rowh = (wv & 1) * 64, colh = (wv >> 1) * 64;
    f32x4 acc[4][4];
    #pragma unroll
    for (int i = 0; i < 4; ++i)
        #pragma unroll
        for (int j = 0; j < 4; ++j) acc[i][j] = (f32x4){0.f, 0.f, 0.f, 0.f};
    int lrow = lane >> 3;
    int srow = wv * 32 + lrow;
    int scol = (((lane & 7) ^ lrow)) * 8;
    const u16* agp = &att[(size_t)(mb * 128 + srow) * C_ + scol];
    const u16* bgp = &wo[(size_t)(nb * 128 + srow) * C_ + scol];
    int rsw = l15 & 7;
    for (int k0 = 0; k0 < C_; k0 += 64) {
        #pragma unroll
        for (int j = 0; j < 4; ++j) {
            GLL(agp + (size_t)(j * 8) * C_ + k0, &Al[wv * 32 + j * 8][0]);
            GLL(bgp + (size_t)(j * 8) * C_ + k0, &Bl[wv * 32 + j * 8][0]);
        }
        __syncthreads();
        #pragma unroll
        for (int ks = 0; ks < 2; ++ks) {
            int cbl = (((ks << 2) | quad) ^ rsw) * 8;
            bf16x8 af[4], bf[4];
            #pragma unroll
            for (int mt = 0; mt < 4; ++mt)
                af[mt] = *(const bf16x8*)&Al[rowh + mt * 16 + l15][cbl];
            #pragma unroll
            for (int nt = 0; nt < 4; ++nt)
                bf[nt] = *(const bf16x8*)&Bl[colh + nt * 16 + l15][cbl];
            #pragma unroll
            for (int mt = 0; mt < 4; ++mt)
                #pragma unroll
                for (int nt = 0; nt < 4; ++nt)
                    acc[mt][nt] = __builtin_amdgcn_mfma_f32_16x16x32_bf16(af[mt], bf[nt], acc[mt][nt], 0, 0, 0);
        }
        __syncthreads();
    }
    #pragma unroll
    for (int nt = 0; nt < 4; ++nt) {
        int n = nb * 128 + colh + nt * 16 + l15;
        float bias = bo[n];
        #pragma unroll
        for (int mt = 0; mt < 4; ++mt)
            #pragma unroll
            for (int r = 0; r < 4; ++r) {
                int m = mb * 128 + rowh + mt * 16 + quad * 4 + r;
                out[(size_t)m * C_ + n] = acc[mt][nt][r] + bias;
            }
    }
}

extern "C" void kernel_launch(void* const* d_in, const int* in_sizes, int n_in,
                              void* d_out, int out_size, void* d_ws, size_t ws_size,
                              hipStream_t stream) {
    const float* x  = (const float*)d_in[0];
    const float* Wq = (const float*)d_in[1];
    const float* Wk = (const float*)d_in[2];
    const float* Wv = (const float*)d_in[3];
    const float* Wo = (const float*)d_in[4];
    const float* bo = (const float*)d_in[5];
    float* out = (float*)d_out;
    char* ws = (char*)d_ws;
    u16* xbf  = (u16*)(ws + (size_t)0);           // 16 MB  x bf16 [8192,1024]
    u16* wt   = (u16*)(ws + ((size_t)16 << 20));  //  6 MB  W qkv [3072,1024] bf16
    u16* wobf = (u16*)(ws + ((size_t)22 << 20));  //  2 MB  Wo bf16 [1024,1024]
    u16* qb   = (u16*)(ws + ((size_t)24 << 20));  // 16 MB  q [BH,T,D]
    u16* kb   = (u16*)(ws + ((size_t)40 << 20));  // 16 MB  k [BH,T,D]
    u16* vtb  = (u16*)(ws + ((size_t)56 << 20));  // 16 MB  v^T [BH,D,T] (written by qkv_gemm)
    u16* attb = (u16*)(ws + ((size_t)72 << 20));  // 16 MB  att out [B*T,C]

    hipLaunchKernelGGL(prep, dim3(9984), dim3(256), 0, stream, x, Wo, Wq, Wk, Wv, xbf, wobf, wt);
    hipLaunchKernelGGL(qkv_gemm, dim3(512), dim3(512), 0, stream, xbf, wt, qb, kb, vtb);
    hipLaunchKernelGGL(attn, dim3(BH, 16), dim3(256), 0, stream, qb, kb, vtb, attb);
    hipLaunchKernelGGL(out_gemm, dim3(BT / 128, C_ / 128), dim3(256), 0, stream, attb, wobf, bo, out);
}

// Round 2
// 230.059 us; speedup vs baseline: 1.0480x; 1.0480x over previous
//
#include <hip/hip_runtime.h>
#include <hip/hip_bf16.h>
#include <math.h>

#define B_ 4
#define T_ 2048
#define C_ 1024
#define H_ 16
#define D_ 64
#define BT (B_*T_)
#define BH (B_*H_)

typedef __bf16 bf16x8 __attribute__((ext_vector_type(8)));
typedef __bf16 bf16x4 __attribute__((ext_vector_type(4)));
typedef float f32x4 __attribute__((ext_vector_type(4)));
typedef unsigned short u16;
typedef u16 u16x8 __attribute__((ext_vector_type(8)));

// async global->LDS, 16B/lane; LDS dest = wave-uniform base + lane*16
#define GLL(g, l) __builtin_amdgcn_global_load_lds( \
    (const __attribute__((address_space(1))) unsigned int*)(g), \
    (__attribute__((address_space(3))) unsigned int*)(l), 16, 0, 0)

#define SCALE2 0.04508422f  // C^-0.5 * log2(e), folded into Wq

#define SBAR()   do { asm volatile("" ::: "memory"); __builtin_amdgcn_s_barrier(); asm volatile("" ::: "memory"); } while (0)
#define WAITV(n) asm volatile("s_waitcnt vmcnt(" #n ")" ::: "memory")
#define LGKM0()  asm volatile("s_waitcnt lgkmcnt(0)" ::: "memory")

__device__ __forceinline__ u16 f2b(float f) {
    union { float f; unsigned u; } v; v.f = f;
    unsigned r = v.u + 0x7fffu + ((v.u >> 16) & 1u);
    return (u16)(r >> 16);
}

// ---- fused preprocessing: cast x, cast Wo, transpose+scale Wq/Wk/Wv ------
// blocks [0,8192): x fp32->bf16 ; [8192,9216): Wo ; [9216,9984): transpose_w
__global__ __launch_bounds__(256) void prep(const float* __restrict__ x,
                                            const float* __restrict__ Wo,
                                            const float* __restrict__ Wq,
                                            const float* __restrict__ Wk,
                                            const float* __restrict__ Wv,
                                            u16* __restrict__ xbf,
                                            u16* __restrict__ wobf,
                                            u16* __restrict__ wt) {
    __shared__ u16 lds[64][72];
    int bid = blockIdx.x, tid = threadIdx.x;
    if (bid < 8192) {
        int g = bid * 256 + tid;
        float4 v = ((const float4*)x)[g];
        ushort4 o;
        o.x = f2b(v.x); o.y = f2b(v.y); o.z = f2b(v.z); o.w = f2b(v.w);
        ((ushort4*)xbf)[g] = o;
        return;
    }
    if (bid < 9216) {
        int g = (bid - 8192) * 256 + tid;
        float4 v = ((const float4*)Wo)[g];
        ushort4 o;
        o.x = f2b(v.x); o.y = f2b(v.y); o.z = f2b(v.z); o.w = f2b(v.w);
        ((ushort4*)wobf)[g] = o;
        return;
    }
    int id = bid - 9216;              // 0..767
    int cb = id & 15, h = (id >> 4) & 15, w = id >> 8;
    const float* W = (w == 0) ? Wq : (w == 1) ? Wk : Wv;
    float sc = (w == 0) ? SCALE2 : 1.0f;
    int c0 = cb * 64;
    {
        int col = (tid & 15) * 4;
        for (int cc = 0; cc < 4; ++cc) {
            int r = (tid >> 4) + cc * 16;
            float4 v = *(const float4*)&W[(size_t)(h * C_ + c0 + r) * D_ + col];
            lds[r][col + 0] = f2b(v.x * sc); lds[r][col + 1] = f2b(v.y * sc);
            lds[r][col + 2] = f2b(v.z * sc); lds[r][col + 3] = f2b(v.w * sc);
        }
    }
    __syncthreads();
    {
        int tcol = (tid & 7) * 8;
        for (int cc = 0; cc < 2; ++cc) {
            int d = (tid >> 3) + cc * 32;
            u16x8 t;
            for (int j = 0; j < 8; ++j) t[j] = lds[tcol + j][d];
            *(u16x8*)&wt[(((size_t)(w * H_ + h) * D_ + d) * C_) + c0 + tcol] = t;
        }
    }
}

// ------- fused QKV GEMM, 8-phase counted-vmcnt schedule -------------------
// x[8192,1024] x wt[3072,1024]^T -> q,k [BH,T,D]; V transposed to vt [BH,D,T].
// BM=256 BN=192 BK=64, 512 thr = 8 waves (2M x 4N), grid 512 = (32 mb, 16 nb).
// BLOCK MAPPING (R2 fix): mb-FASTEST, NO swizzle. Dispatch round-robins XCDs
// (xcd = orig%8 = mb%8), so each XCD owns a fixed 4-panel A slice
// (4 x 512 KB = 2 MB, L2-resident) reused across all 16 nb sweeps — the same
// accidental-optimal locality the old 128-tile grid had. R1's swizzle gave
// each XCD ALL of A (16 MB) -> L2 thrash, FETCH 49->134 MB, MFMA starved.
// Per K-tile, 4 phases; B-frags ds_read only in p0 (held in regs p1-p3):
//   p0: read B(all)+A(r0,1); stage A(t+1)u0,u1 -> nxt    | 12 MFMA
//   p1: read A(r2,3);        stage A(t+1)u2,u3 -> nxt    | 12 MFMA
//   p2: read A(r4,5);        stage B(t+2)u0,u1 -> cur.B  | 12 MFMA
//   p3: read A(r6,7);        stage B(t+2)u2    -> cur.B  | 12 MFMA, vmcnt(3)
// vmcnt(3) leaves B(t+2)'s 3 GLL in flight across the tile boundary.
#define NT_ 16
__global__ __launch_bounds__(512, 2) void qkv_gemm(const u16* __restrict__ xbf,
                                                   const u16* __restrict__ wt,
                                                   u16* __restrict__ q, u16* __restrict__ k,
                                                   u16* __restrict__ vt) {
    __shared__ u16 Al[2][256][64];   // 64 KiB
    __shared__ u16 Bl[2][192][64];   // 48 KiB
    int orig = blockIdx.x;
    int mb = orig & 31, nb = orig >> 5;       // mb-fastest: xcd = mb%8, A slice L2-resident
    int tid = threadIdx.x, wid = tid >> 6, lane = tid & 63;
    int l15 = lane & 15, quad = lane >> 4;
    int wm = wid >> 2, wn = wid & 3;          // wave tile: 128 x 48
    int srow8 = wid * 8 + (lane >> 3);        // 0..63: block-cooperative 64-row unit
    int scol8 = ((lane & 7) ^ (lane >> 3)) * 8;  // pre-swizzled source column
    const u16* Ag = xbf + (size_t)(mb * 256 + srow8) * C_ + scol8;
    const u16* Bg = wt  + (size_t)(nb * 192 + srow8) * C_ + scol8;
    int rsw = l15 & 7;
    f32x4 acc[8][3];
    #pragma unroll
    for (int i = 0; i < 8; ++i)
        #pragma unroll
        for (int j = 0; j < 3; ++j) acc[i][j] = (f32x4){0.f, 0.f, 0.f, 0.f};

#define STAGE_A(buf, u, kt) GLL(Ag + (size_t)((u) * 64) * C_ + (kt) * 64, &Al[buf][(u) * 64 + wid * 8][0])
#define STAGE_B(buf, u, kt) GLL(Bg + (size_t)((u) * 64) * C_ + (kt) * 64, &Bl[buf][(u) * 64 + wid * 8][0])
#define LOAD_A(R0) do { \
    _Pragma("unroll") for (int r = 0; r < 2; ++r) \
    _Pragma("unroll") for (int ks = 0; ks < 2; ++ks) \
        a[r][ks] = *(const bf16x8*)&Ac[wm * 128 + ((R0) + r) * 16 + l15][(((ks << 2) | quad) ^ rsw) * 8]; \
} while (0)
#define MFMA_PH(R0) do { \
    __builtin_amdgcn_s_setprio(1); \
    _Pragma("unroll") for (int ks = 0; ks < 2; ++ks) \
    _Pragma("unroll") for (int fc = 0; fc < 3; ++fc) \
    _Pragma("unroll") for (int r = 0; r < 2; ++r) \
        acc[(R0) + r][fc] = __builtin_amdgcn_mfma_f32_16x16x32_bf16(a[r][ks], b[fc][ks], acc[(R0) + r][fc], 0, 0, 0); \
    __builtin_amdgcn_s_setprio(0); \
} while (0)

    // prologue: A(t0) u0-3, B(t0) u0-2, B(t1) u0-2 = 10 GLL; first 7 must land
    STAGE_A(0, 0, 0); STAGE_A(0, 1, 0); STAGE_A(0, 2, 0); STAGE_A(0, 3, 0);
    STAGE_B(0, 0, 0); STAGE_B(0, 1, 0); STAGE_B(0, 2, 0);
    STAGE_B(1, 0, 1); STAGE_B(1, 1, 1); STAGE_B(1, 2, 1);
    WAITV(3);
    SBAR();

    for (int t = 0; t < NT_; ++t) {
        int cur = t & 1, nxt = cur ^ 1;
        const u16 (*Ac)[64] = Al[cur];
        const u16 (*Bc)[64] = Bl[cur];
        bf16x8 b[3][2], a[2][2];
        // ---- phase 0: all B frags + A rows 0,1 -------------------------
        #pragma unroll
        for (int fc = 0; fc < 3; ++fc)
            #pragma unroll
            for (int ks = 0; ks < 2; ++ks)
                b[fc][ks] = *(const bf16x8*)&Bc[wn * 48 + fc * 16 + l15][(((ks << 2) | quad) ^ rsw) * 8];
        LOAD_A(0);
        if (t + 1 < NT_) { STAGE_A(nxt, 0, t + 1); STAGE_A(nxt, 1, t + 1); }
        SBAR(); LGKM0();
        MFMA_PH(0);
        SBAR();
        // ---- phase 1: A rows 2,3 ---------------------------------------
        LOAD_A(2);
        if (t + 1 < NT_) { STAGE_A(nxt, 2, t + 1); STAGE_A(nxt, 3, t + 1); }
        SBAR(); LGKM0();
        MFMA_PH(2);
        SBAR();
        // ---- phase 2: A rows 4,5; cur.B is dead after p0 ---------------
        LOAD_A(4);
        if (t + 2 < NT_) { STAGE_B(cur, 0, t + 2); STAGE_B(cur, 1, t + 2); }
        SBAR(); LGKM0();
        MFMA_PH(4);
        SBAR();
        // ---- phase 3: A rows 6,7; counted vmcnt at tile boundary -------
        LOAD_A(6);
        if (t + 2 < NT_) STAGE_B(cur, 2, t + 2);
        SBAR(); LGKM0();
        MFMA_PH(6);
        if (t + 2 < NT_)      WAITV(3);
        else if (t + 1 < NT_) WAITV(0);
        SBAR();
    }
#undef STAGE_A
#undef STAGE_B
#undef LOAD_A
#undef MFMA_PH

    // epilogue: n = nb*192 + wn*48 + fc*16 + l15 decodes to {q|k|v, head, d}
    int bb = mb >> 3;                       // 256-row block within one batch
    int mbase0 = mb * 256 + wm * 128;
    #pragma unroll
    for (int fc = 0; fc < 3; ++fc) {
        int n0 = nb * 192 + wn * 48 + fc * 16;
        int wsel = n0 >> 10, hh = (n0 >> 6) & 15, d0 = n0 & 63;
        if (wsel == 2) {
            // V: store transposed to vt[bh][d][t], 4 consecutive t per pack
            u16* vrow = vt + ((size_t)((bb * H_ + hh) * D_) + d0 + l15) * T_;
            #pragma unroll
            for (int fr = 0; fr < 8; ++fr) {
                int tbase = ((mbase0 + fr * 16) & (T_ - 1)) + quad * 4;
                bf16x4 w;
                #pragma unroll
                for (int r = 0; r < 4; ++r) w[r] = (__bf16)acc[fr][fc][r];
                *(bf16x4*)&vrow[tbase] = w;
            }
        } else {
            u16* op = wsel ? k : q;
            #pragma unroll
            for (int fr = 0; fr < 8; ++fr)
                #pragma unroll
                for (int r = 0; r < 4; ++r) {
                    int m = mbase0 + fr * 16 + quad * 4 + r;
                    int tt = m & (T_ - 1);
                    op[((size_t)(bb * H_ + hh) * T_ + tt) * D_ + d0 + l15] = f2b(acc[fr][fc][r]);
                }
        }
    }
}

// -------- flash attention v5: fixed-base softmax (no online max) ----------
// P = exp2(s) directly: scores pre-scaled into exp2 domain; |s| << 128 for
// N(0,1)-class inputs so no overflow; max-subtraction cancels in P/l.
// Block-cooperative GLL K/V staging, double-buffered, one barrier/tile,
// XCD-affine grid (BH,16).
__global__ __launch_bounds__(256, 2) void attn(const u16* __restrict__ q, const u16* __restrict__ kk,
                                               const u16* __restrict__ vt, u16* __restrict__ att) {
    __shared__ u16 Kl[2][64][64];
    __shared__ u16 Vl[2][64][64];
    __shared__ u16 Pl[4][32][72];
    int bh = blockIdx.x, c = 15 - blockIdx.y;
    int b = bh >> 4, h = bh & 15;
    int tid = threadIdx.x, wid = tid >> 6, lane = tid & 63, l15 = lane & 15, quad = lane >> 4;
    const u16* qbase = q + (size_t)bh * T_ * D_;
    const u16* kbase = kk + (size_t)bh * T_ * D_;
    const u16* vbase = vt + (size_t)bh * D_ * T_;
    u16* pw = &Pl[wid][0][0];
    bf16x8 ones;
    #pragma unroll
    for (int j = 0; j < 8; ++j) ones[j] = (__bf16)1.0f;
    int r8 = lane >> 3, cbl_st = lane & 7;
    int csrc = ((cbl_st ^ r8)) * 8;
    int strow = wid * 16 + r8;
    int rsw = l15 & 7;

    int R0q = c * 128 + wid * 32;
    int ktb = 2 * c + 1;
    int kmax_w = R0q >> 6;
    bf16x8 bq[2][2];
    #pragma unroll
    for (int qt = 0; qt < 2; ++qt)
        #pragma unroll
        for (int kd = 0; kd < 2; ++kd)
            bq[qt][kd] = *(const bf16x8*)&qbase[(size_t)(R0q + qt * 16 + l15) * D_ + kd * 32 + quad * 8];
    f32x4 o[4][2];
    f32x4 lacc[2];
    #pragma unroll
    for (int dt = 0; dt < 4; ++dt)
        #pragma unroll
        for (int qt = 0; qt < 2; ++qt) o[dt][qt] = (f32x4){0.f, 0.f, 0.f, 0.f};
    lacc[0] = (f32x4){0.f, 0.f, 0.f, 0.f};
    lacc[1] = (f32x4){0.f, 0.f, 0.f, 0.f};
    #pragma unroll
    for (int j = 0; j < 2; ++j) {
        GLL(kbase + (size_t)(strow + j * 8) * D_ + csrc, &Kl[0][wid * 16 + j * 8][0]);
        GLL(vbase + (size_t)(strow + j * 8) * T_ + csrc, &Vl[0][wid * 16 + j * 8][0]);
    }
    __syncthreads();
    for (int kt = 0; kt <= ktb; ++kt) {
        int cur = kt & 1;
        if (kt < ktb) {
            int kn = (kt + 1) * 64;
            #pragma unroll
            for (int j = 0; j < 2; ++j) {
                GLL(kbase + (size_t)(kn + strow + j * 8) * D_ + csrc, &Kl[cur ^ 1][wid * 16 + j * 8][0]);
                GLL(vbase + (size_t)(strow + j * 8) * T_ + kn + csrc, &Vl[cur ^ 1][wid * 16 + j * 8][0]);
            }
        }
        if (kt <= kmax_w) {
            int k0 = kt * 64;
            f32x4 sS[4][2];
            #pragma unroll
            for (int kvt = 0; kvt < 4; ++kvt)
                #pragma unroll
                for (int qt = 0; qt < 2; ++qt) sS[kvt][qt] = (f32x4){0.f, 0.f, 0.f, 0.f};
            #pragma unroll
            for (int kd = 0; kd < 2; ++kd) {
                int cblk = (((kd << 2) | quad) ^ rsw) * 8;
                bf16x8 akf[4];
                #pragma unroll
                for (int kvt = 0; kvt < 4; ++kvt)
                    akf[kvt] = *(const bf16x8*)&Kl[cur][kvt * 16 + l15][cblk];
                #pragma unroll
                for (int kvt = 0; kvt < 4; ++kvt)
                    #pragma unroll
                    for (int qt = 0; qt < 2; ++qt)
                        sS[kvt][qt] = __builtin_amdgcn_mfma_f32_16x16x32_bf16(akf[kvt], bq[qt][kd], sS[kvt][qt], 0, 0, 0);
            }
            if (kt == kmax_w) {  // causal mask, diagonal tile only
                #pragma unroll
                for (int qt = 0; qt < 2; ++qt) {
                    int qabs = R0q + qt * 16 + l15;
                    #pragma unroll
                    for (int kvt = 0; kvt < 4; ++kvt) {
                        int kvb = k0 + kvt * 16 + quad * 4;
                        #pragma unroll
                        for (int r = 0; r < 4; ++r)
                            if (kvb + r > qabs) sS[kvt][qt][r] = -INFINITY;
                    }
                }
            }
            // fixed-base softmax: P = exp2(s); exp2(-inf) = 0 handles the mask
            #pragma unroll
            for (int kvt = 0; kvt < 4; ++kvt)
                #pragma unroll
                for (int qt = 0; qt < 2; ++qt)
                    #pragma unroll
                    for (int r = 0; r < 4; ++r)
                        sS[kvt][qt][r] = __builtin_amdgcn_exp2f(sS[kvt][qt][r]);
            // P -> wave-private LDS: P[qrow][kv] (bf16)
            #pragma unroll
            for (int qt = 0; qt < 2; ++qt)
                #pragma unroll
                for (int kvt = 0; kvt < 4; ++kvt) {
                    bf16x4 w;
                    #pragma unroll
                    for (int r = 0; r < 4; ++r) w[r] = (__bf16)sS[kvt][qt][r];
                    *(bf16x4*)&pw[(qt * 16 + l15) * 72 + kvt * 16 + quad * 4] = w;
                }
            // O^T += V^T . P^T ; l += ones . P^T
            #pragma unroll
            for (int ks = 0; ks < 2; ++ks) {
                int cblk = (((ks << 2) | quad) ^ rsw) * 8;
                bf16x8 avf[4];
                #pragma unroll
                for (int dt = 0; dt < 4; ++dt)
                    avf[dt] = *(const bf16x8*)&Vl[cur][dt * 16 + l15][cblk];
                #pragma unroll
                for (int qt = 0; qt < 2; ++qt) {
                    bf16x8 bp = *(const bf16x8*)&pw[(qt * 16 + l15) * 72 + ks * 32 + quad * 8];
                    #pragma unroll
                    for (int dt = 0; dt < 4; ++dt)
                        o[dt][qt] = __builtin_amdgcn_mfma_f32_16x16x32_bf16(avf[dt], bp, o[dt][qt], 0, 0, 0);
                    lacc[qt] = __builtin_amdgcn_mfma_f32_16x16x32_bf16(ones, bp, lacc[qt], 0, 0, 0);
                }
            }
        }
        __syncthreads();
    }
    #pragma unroll
    for (int qt = 0; qt < 2; ++qt) {
        float rl = __builtin_amdgcn_rcpf(lacc[qt][0]);
        int qabs = R0q + qt * 16 + l15;
        #pragma unroll
        for (int dt = 0; dt < 4; ++dt) {
            bf16x4 w;
            #pragma unroll
            for (int r = 0; r < 4; ++r) w[r] = (__bf16)(o[dt][qt][r] * rl);
            *(bf16x4*)&att[(size_t)(b * T_ + qabs) * C_ + h * 64 + dt * 16 + quad * 4] = w;
        }
    }
}

// ------ out proj: att[8192,1024] x wo[1024,1024]^T + bo -> fp32 out -------
// Single-buffer GLL staging (R8 config).
__global__ __launch_bounds__(256) void out_gemm(const u16* __restrict__ att,
                                                const u16* __restrict__ wo,
                                                const float* __restrict__ bo,
                                                float* __restrict__ out) {
    __shared__ u16 Al[128][64];
    __shared__ u16 Bl[128][64];
    int mb = blockIdx.x, nb = blockIdx.y;
    int tid = threadIdx.x, wv = tid >> 6, lane = tid & 63, l15 = lane & 15, quad = lane >> 4;
    int rowh = (wv & 1) * 64, colh = (wv >> 1) * 64;
    f32x4 acc[4][4];
    #pragma unroll
    for (int i = 0; i < 4; ++i)
        #pragma unroll
        for (int j = 0; j < 4; ++j) acc[i][j] = (f32x4){0.f, 0.f, 0.f, 0.f};
    int lrow = lane >> 3;
    int srow = wv * 32 + lrow;
    int scol = (((lane & 7) ^ lrow)) * 8;
    const u16* agp = &att[(size_t)(mb * 128 + srow) * C_ + scol];
    const u16* bgp = &wo[(size_t)(nb * 128 + srow) * C_ + scol];
    int rsw = l15 & 7;
    for (int k0 = 0; k0 < C_; k0 += 64) {
        #pragma unroll
        for (int j = 0; j < 4; ++j) {
            GLL(agp + (size_t)(j * 8) * C_ + k0, &Al[wv * 32 + j * 8][0]);
            GLL(bgp + (size_t)(j * 8) * C_ + k0, &Bl[wv * 32 + j * 8][0]);
        }
        __syncthreads();
        #pragma unroll
        for (int ks = 0; ks < 2; ++ks) {
            int cbl = (((ks << 2) | quad) ^ rsw) * 8;
            bf16x8 af[4], bf[4];
            #pragma unroll
            for (int mt = 0; mt < 4; ++mt)
                af[mt] = *(const bf16x8*)&Al[rowh + mt * 16 + l15][cbl];
            #pragma unroll
            for (int nt = 0; nt < 4; ++nt)
                bf[nt] = *(const bf16x8*)&Bl[colh + nt * 16 + l15][cbl];
            #pragma unroll
            for (int mt = 0; mt < 4; ++mt)
                #pragma unroll
                for (int nt = 0; nt < 4; ++nt)
                    acc[mt][nt] = __builtin_amdgcn_mfma_f32_16x16x32_bf16(af[mt], bf[nt], acc[mt][nt], 0, 0, 0);
        }
        __syncthreads();
    }
    #pragma unroll
    for (int nt = 0; nt < 4; ++nt) {
        int n = nb * 128 + colh + nt * 16 + l15;
        float bias = bo[n];
        #pragma unroll
        for (int mt = 0; mt < 4; ++mt)
            #pragma unroll
            for (int r = 0; r < 4; ++r) {
                int m = mb * 128 + rowh + mt * 16 + quad * 4 + r;
                out[(size_t)m * C_ + n] = acc[mt][nt][r] + bias;
            }
    }
}

extern "C" void kernel_launch(void* const* d_in, const int* in_sizes, int n_in,
                              void* d_out, int out_size, void* d_ws, size_t ws_size,
                              hipStream_t stream) {
    const float* x  = (const float*)d_in[0];
    const float* Wq = (const float*)d_in[1];
    const float* Wk = (const float*)d_in[2];
    const float* Wv = (const float*)d_in[3];
    const float* Wo = (const float*)d_in[4];
    const float* bo = (const float*)d_in[5];
    float* out = (float*)d_out;
    char* ws = (char*)d_ws;
    u16* xbf  = (u16*)(ws + (size_t)0);           // 16 MB  x bf16 [8192,1024]
    u16* wt   = (u16*)(ws + ((size_t)16 << 20));  //  6 MB  W qkv [3072,1024] bf16
    u16* wobf = (u16*)(ws + ((size_t)22 << 20));  //  2 MB  Wo bf16 [1024,1024]
    u16* qb   = (u16*)(ws + ((size_t)24 << 20));  // 16 MB  q [BH,T,D]
    u16* kb   = (u16*)(ws + ((size_t)40 << 20));  // 16 MB  k [BH,T,D]
    u16* vtb  = (u16*)(ws + ((size_t)56 << 20));  // 16 MB  v^T [BH,D,T] (written by qkv_gemm)
    u16* attb = (u16*)(ws + ((size_t)72 << 20));  // 16 MB  att out [B*T,C]

    hipLaunchKernelGGL(prep, dim3(9984), dim3(256), 0, stream, x, Wo, Wq, Wk, Wv, xbf, wobf, wt);
    hipLaunchKernelGGL(qkv_gemm, dim3(512), dim3(512), 0, stream, xbf, wt, qb, kb, vtb);
    hipLaunchKernelGGL(attn, dim3(BH, 16), dim3(256), 0, stream, qb, kb, vtb, attb);
    hipLaunchKernelGGL(out_gemm, dim3(BT / 128, C_ / 128), dim3(256), 0, stream, attb, wobf, bo, out);
}